// Round 21
// baseline (4474.390 us; speedup 1.0000x reference)
//
#include <hip/hip_runtime.h>

typedef __bf16 bf16x8 __attribute__((ext_vector_type(8)));
typedef float  f32x4  __attribute__((ext_vector_type(4)));
typedef short  s16x8  __attribute__((ext_vector_type(8)));
typedef unsigned int u32;
#define AS1 __attribute__((address_space(1)))
#define AS3 __attribute__((address_space(3)))

#define E_ 1024
#define T_ 1024
#define B_ 4
#define L_ 8
#define V_ 32000
#define M_ (B_*T_)   /* 4096 rows */

static __device__ __forceinline__ ushort f2bf(float f) {
  return __builtin_bit_cast(ushort, (__bf16)f);
}
static __device__ __forceinline__ float bf2f(ushort u) {
  u32 t = (u32)u << 16;
  return __builtin_bit_cast(float, t);
}

// inline-asm LDS read (compiler-invisible scheduling; waits are manual)
static __device__ __forceinline__ bf16x8 dsr(const ushort* p) {
  u32 a = (u32)(size_t)(const AS3 ushort*)p;
  bf16x8 d;
  asm volatile("ds_read_b128 %0, %1" : "=v"(d) : "v"(a));
  return d;
}

// ---------------- LN core ----------------
static __device__ __forceinline__ void ln_core(float4 v, int t,
    const float* __restrict__ w, const float* __restrict__ b,
    ushort* __restrict__ out, size_t row) {
  float s  = v.x + v.y + v.z + v.w;
  float s2 = v.x*v.x + v.y*v.y + v.z*v.z + v.w*v.w;
  #pragma unroll
  for (int o = 32; o > 0; o >>= 1) { s += __shfl_down(s, o); s2 += __shfl_down(s2, o); }
  __shared__ float sh[8];
  int wv = t >> 6;
  if ((t & 63) == 0) { sh[wv] = s; sh[4 + wv] = s2; }
  __syncthreads();
  s  = sh[0] + sh[1] + sh[2] + sh[3];
  s2 = sh[4] + sh[5] + sh[6] + sh[7];
  float mean = s * (1.f / E_);
  float var  = s2 * (1.f / E_) - mean * mean;
  float inv  = rsqrtf(var + 1e-5f);
  float4 wv4 = ((const float4*)w)[t];
  float4 bv4 = ((const float4*)b)[t];
  ushort* op = out + row * E_ + t * 4;
  op[0] = f2bf((v.x - mean) * inv * wv4.x + bv4.x);
  op[1] = f2bf((v.y - mean) * inv * wv4.y + bv4.y);
  op[2] = f2bf((v.z - mean) * inv * wv4.z + bv4.z);
  op[3] = f2bf((v.w - mean) * inv * wv4.w + bv4.w);
}

// ---------------- startup: weight casts (5 tensors) + embed+ln1, 1 dispatch ------
__global__ __launch_bounds__(256) void start_k(
    const float* __restrict__ a0, const float* __restrict__ a1,
    const float* __restrict__ a2, const float* __restrict__ a3,
    const float* __restrict__ a4,
    ushort* __restrict__ o0, ushort* __restrict__ o1, ushort* __restrict__ o2,
    ushort* __restrict__ o3, ushort* __restrict__ o4,
    const int* __restrict__ idx, const float* __restrict__ wte,
    const float* __restrict__ wpe, const float* __restrict__ lw,
    const float* __restrict__ lb, float* __restrict__ x,
    ushort* __restrict__ hout) {
  int bid = blockIdx.x;
  if (bid >= 65152) {                 // embed + ln1(layer0): 4096 blocks
    int row = bid - 65152;
    int tok = idx[row];
    int t = row & (T_ - 1);
    int c = threadIdx.x;
    float4 a = ((const float4*)(wte + (size_t)tok * E_))[c];
    float4 p = ((const float4*)(wpe + (size_t)t * E_))[c];
    float4 v; v.x = a.x + p.x; v.y = a.y + p.y; v.z = a.z + p.z; v.w = a.w + p.w;
    ((float4*)(x + (size_t)row * E_))[c] = v;
    ln_core(v, c, lw, lb, hout, (size_t)row);
    return;
  }
  const float* in; ushort* out; int base;
  if (bid < 12288)      { in = a0; out = o0; base = bid; }
  else if (bid < 16384) { in = a1; out = o1; base = bid - 12288; }
  else if (bid < 32768) { in = a2; out = o2; base = bid - 16384; }
  else if (bid < 49152) { in = a3; out = o3; base = bid - 32768; }
  else                  { in = a4; out = o4; base = bid - 49152; }
  size_t i = ((size_t)base * 256 + threadIdx.x) * 8;
  float4 a = *(const float4*)(in + i);
  float4 b = *(const float4*)(in + i + 4);
  float v[8] = {a.x, a.y, a.z, a.w, b.x, b.y, b.z, b.w};
  union { s16x8 v; ushort u[8]; } pk;
  #pragma unroll
  for (int j = 0; j < 8; ++j) pk.u[j] = f2bf(v[j]);
  *(s16x8*)(out + i) = pk.v;
}

// ---------------- layernorm (f32 in, bf16 out) ----------------
__global__ __launch_bounds__(256) void ln_k(const float* __restrict__ x,
    const float* __restrict__ w, const float* __restrict__ b,
    ushort* __restrict__ out) {
  int row = blockIdx.x;
  int t = threadIdx.x;
  float4 v = ((const float4*)(x + (size_t)row * E_))[t];
  ln_core(v, t, w, b, out, (size_t)row);
}

// ---------------- split-K reduce (bf16 partials) + bias + residual + LN ----------
__global__ __launch_bounds__(256) void redln_k(const ushort* __restrict__ p,
    const float* __restrict__ bias, float* __restrict__ x,
    const float* __restrict__ w, const float* __restrict__ b,
    ushort* __restrict__ out) {
  int row = blockIdx.x;
  int t = threadIdx.x;
  float4 v = ((const float4*)(x + (size_t)row * E_))[t];
  float4 bb = ((const float4*)bias)[t];
  v.x += bb.x; v.y += bb.y; v.z += bb.z; v.w += bb.w;
  #pragma unroll
  for (int sk = 0; sk < 4; ++sk) {
    const ushort* q = p + ((size_t)sk * M_ + row) * E_ + t * 4;
    v.x += bf2f(q[0]); v.y += bf2f(q[1]); v.z += bf2f(q[2]); v.w += bf2f(q[3]);
  }
  ((float4*)(x + (size_t)row * E_))[t] = v;
  ln_core(v, t, w, b, out, (size_t)row);
}

// ======================================================================
// gemm8 (lm_head only): 256x256, m201-style 8-phase schedule (r16, proven).
// ======================================================================
template<int BUF, int MH, int NH, int RA, int RB, int VM, typename F>
static __device__ __forceinline__ void ph8(
    const ushort* AL, const ushort* BL,
    bf16x8 (&av)[2][4][2], bf16x8 (&bv)[2][2][2],
    int arow, int brow, int ca0, int ca1, f32x4 (&acc)[8][4], F&& stage) {
  if (RA) {
    #pragma unroll
    for (int mfi = 0; mfi < 4; ++mfi) {
      av[MH][mfi][0] = dsr(&AL[(BUF*2+MH)*8192 + arow + mfi*1024 + ca0]);
      av[MH][mfi][1] = dsr(&AL[(BUF*2+MH)*8192 + arow + mfi*1024 + ca1]);
    }
  }
  if (RB) {
    #pragma unroll
    for (int nfi = 0; nfi < 2; ++nfi) {
      bv[NH][nfi][0] = dsr(&BL[(BUF*2+NH)*8192 + brow + nfi*1024 + ca0]);
      bv[NH][nfi][1] = dsr(&BL[(BUF*2+NH)*8192 + brow + nfi*1024 + ca1]);
    }
  }
  stage();
  __builtin_amdgcn_s_barrier();
  asm volatile("s_waitcnt lgkmcnt(0)");
  __builtin_amdgcn_sched_barrier(0);
  __builtin_amdgcn_s_setprio(1);
  #pragma unroll
  for (int ks = 0; ks < 2; ++ks)
    #pragma unroll
    for (int mfi = 0; mfi < 4; ++mfi)
      #pragma unroll
      for (int nfi = 0; nfi < 2; ++nfi)
        acc[MH*4+mfi][NH*2+nfi] = __builtin_amdgcn_mfma_f32_16x16x32_bf16(
            av[MH][mfi][ks], bv[NH][nfi][ks], acc[MH*4+mfi][NH*2+nfi], 0, 0, 0);
  __builtin_amdgcn_s_setprio(0);
  if (VM) asm volatile("s_waitcnt vmcnt(4)");
  __builtin_amdgcn_s_barrier();
  __builtin_amdgcn_sched_barrier(0);
}

#define GLDS(src, dst) __builtin_amdgcn_global_load_lds((const AS1 u32*)(src), (AS3 u32*)(dst), 16, 0, 0)
#define STAGE_A(b, s, t) do { \
  GLDS(ap##s##_0 + (size_t)(t)*64, &AL[((b)*2+(s))*8192 + w*512]); \
  GLDS(ap##s##_1 + (size_t)(t)*64, &AL[((b)*2+(s))*8192 + 4096 + w*512]); } while(0)
#define STAGE_B(b, s, t) do { \
  GLDS(bp##s##_0 + (size_t)(t)*64, &BL[((b)*2+(s))*8192 + w*512]); \
  GLDS(bp##s##_1 + (size_t)(t)*64, &BL[((b)*2+(s))*8192 + 4096 + w*512]); } while(0)

__global__ __launch_bounds__(512, 2)
void gemm8_lm(const ushort* __restrict__ A, const ushort* __restrict__ W,
              float* __restrict__ outf) {
  const int N = V_, K = E_, Kst = E_;
  __shared__ __align__(16) ushort AL[32768];
  __shared__ __align__(16) ushort BL[32768];
  int id  = blockIdx.x;
  int nwg = gridDim.x;
  int swz = (id & 7) * (nwg >> 3) + (id >> 3);
  int bx = swz >> 4, by = swz & 15;
  int bm = by * 256, bn = bx * 256;
  int tid = threadIdx.x;
  int w = tid >> 6, lane = tid & 63;
  int wm = w >> 2, wn = w & 3;
  int g = lane >> 4, lr = lane & 15;
  int sl8 = lane >> 3, sc = lane & 7;
  int cg8 = (sc ^ sl8) * 8;

  int r0 = w * 8 + sl8;
  const ushort* ap0_0 = A + (size_t)(bm +       0 + r0) * Kst + cg8;
  const ushort* ap0_1 = A + (size_t)(bm + 128 + 0 + r0) * Kst + cg8;
  const ushort* ap1_0 = A + (size_t)(bm +      64 + r0) * Kst + cg8;
  const ushort* ap1_1 = A + (size_t)(bm + 128 + 64 + r0) * Kst + cg8;
  int sr0 = r0, sr1 = 64 + r0;
  const ushort* bp0_0 = W + (size_t)(bn + (sr0 >> 5) * 64 +  0 + (sr0 & 31)) * Kst + cg8;
  const ushort* bp0_1 = W + (size_t)(bn + (sr1 >> 5) * 64 +  0 + (sr1 & 31)) * Kst + cg8;
  const ushort* bp1_0 = W + (size_t)(bn + (sr0 >> 5) * 64 + 32 + (sr0 & 31)) * Kst + cg8;
  const ushort* bp1_1 = W + (size_t)(bn + (sr1 >> 5) * 64 + 32 + (sr1 & 31)) * Kst + cg8;

  int NT = K >> 6;
  int NITER = NT >> 1;
  int arow = (wm * 64 + lr) * 64;
  int brow = (wn * 32 + lr) * 64;
  int ca0 = ((0 + g) ^ (lr & 7)) * 8;
  int ca1 = ((4 + g) ^ (lr & 7)) * 8;
  f32x4 acc[8][4] = {};
  bf16x8 av[2][4][2], bv[2][2][2];

  STAGE_A(0, 0, 0); STAGE_A(0, 1, 0); STAGE_B(0, 0, 0); STAGE_B(0, 1, 0);
  STAGE_A(1, 0, 1); STAGE_B(1, 0, 1);
  asm volatile("s_waitcnt vmcnt(0)" ::: "memory");
  __builtin_amdgcn_s_barrier();
  __builtin_amdgcn_sched_barrier(0);

  for (int i = 0; i < NITER; ++i) {
    int t1 = 2 * i + 1;
    int t2 = 2 * i + 2; if (t2 > NT - 1) t2 = NT - 1;
    int t3 = 2 * i + 3; if (t3 > NT - 1) t3 = NT - 1;
    ph8<0,0,0,1,1,0>(AL, BL, av, bv, arow, brow, ca0, ca1, acc, [&]{ STAGE_A(1, 1, t1); });
    ph8<0,0,1,0,1,0>(AL, BL, av, bv, arow, brow, ca0, ca1, acc, [&]{ STAGE_B(1, 1, t1); });
    ph8<0,1,1,1,0,0>(AL, BL, av, bv, arow, brow, ca0, ca1, acc, [&]{ STAGE_A(0, 0, t2); });
    ph8<0,1,0,0,0,1>(AL, BL, av, bv, arow, brow, ca0, ca1, acc, [&]{ STAGE_B(0, 0, t2); });
    ph8<1,0,0,1,1,0>(AL, BL, av, bv, arow, brow, ca0, ca1, acc, [&]{ STAGE_A(0, 1, t2); });
    ph8<1,0,1,0,1,0>(AL, BL, av, bv, arow, brow, ca0, ca1, acc, [&]{ STAGE_B(0, 1, t2); });
    ph8<1,1,1,1,0,0>(AL, BL, av, bv, arow, brow, ca0, ca1, acc, [&]{ STAGE_A(1, 0, t3); });
    ph8<1,1,0,0,0,1>(AL, BL, av, bv, arow, brow, ca0, ca1, acc, [&]{ STAGE_B(1, 0, t3); });
  }

  #pragma unroll
  for (int mf = 0; mf < 8; ++mf)
    #pragma unroll
    for (int reg = 0; reg < 4; ++reg) {
      int row = bm + wm * 128 + mf * 16 + g * 4 + reg;
      #pragma unroll
      for (int nf = 0; nf < 4; ++nf) {
        int col = bn + wn * 64 + nf * 16 + lr;
        outf[(size_t)row * N + col] = acc[mf][nf][reg];
      }
    }
}

// ======================================================================
// gbt2: 128x128, BK=64, conflict-free swizzled LDS, 32KB, 5 blk/CU.
// EPI 1: outf=acc+bias+res | 2: outh=gelu | 3: qkv scatter (V transposed)
// EPI 4: split-K bf16 partials (Kst=4096, K=1024)
// ======================================================================
template<int EPI>
static __device__ __forceinline__
void gbt2_body(const ushort* __restrict__ A, const ushort* __restrict__ W,
               const float* __restrict__ bias, const float* __restrict__ res,
               float* __restrict__ outf, ushort* __restrict__ outh,
               ushort* __restrict__ qb, ushort* __restrict__ kb, ushort* __restrict__ vb,
               int N, int K, int Kst, int gx) {
  __shared__ __align__(16) ushort As[128 * 64];
  __shared__ __align__(16) ushort Ws[128 * 64];
  int id  = blockIdx.x;
  int nwg = gridDim.x;
  int swz = (id & 7) * (nwg >> 3) + (id >> 3);
  int sk = 0;
  if (EPI == 4) { sk = swz >> 8; swz &= 255; }
  int bx = swz / 32, by = swz & 31;
  int bm = by * 128, bn = bx * 128;
  int tid  = threadIdx.x;
  int wave = tid >> 6, lane = tid & 63;
  int wr = wave >> 1, wc = wave & 1;
  int g  = lane >> 4, lr = lane & 15;
  int sl8 = lane >> 3, sc = lane & 7;
  int cg8 = (sc ^ sl8) * 8;
  int r0 = wave * 8 + sl8;

  const ushort* ap = A + (size_t)sk * 1024 + (size_t)(bm + r0) * Kst + cg8;
  const ushort* wp = W + (size_t)sk * 1024 + (size_t)(bn + r0) * Kst + cg8;
  f32x4 acc[4][4] = {};

  for (int k0 = 0; k0 < K; k0 += 64) {
    #pragma unroll
    for (int j = 0; j < 4; ++j) {
      GLDS(ap + (size_t)(j * 32) * Kst + k0, &As[(wave * 8 + j * 32) * 64]);
      GLDS(wp + (size_t)(j * 32) * Kst + k0, &Ws[(wave * 8 + j * 32) * 64]);
    }
    __syncthreads();
    #pragma unroll
    for (int ks = 0; ks < 2; ++ks) {
      int ca = ((ks * 4 + g) ^ (lr & 7)) * 8;
      bf16x8 af[4], bfr[4];
      #pragma unroll
      for (int f = 0; f < 4; ++f) {
        af[f]  = __builtin_bit_cast(bf16x8, *(const s16x8*)&As[(wr * 64 + f * 16 + lr) * 64 + ca]);
        bfr[f] = __builtin_bit_cast(bf16x8, *(const s16x8*)&Ws[(wc * 64 + f * 16 + lr) * 64 + ca]);
      }
      #pragma unroll
      for (int mf = 0; mf < 4; ++mf)
        #pragma unroll
        for (int nf = 0; nf < 4; ++nf)
          acc[mf][nf] = __builtin_amdgcn_mfma_f32_16x16x32_bf16(af[mf], bfr[nf], acc[mf][nf], 0, 0, 0);
    }
    __syncthreads();
  }

  if (EPI == 3 && (bn >> 10) == 2) {
    #pragma unroll
    for (int mf = 0; mf < 4; ++mf) {
      int row = bm + wr * 64 + mf * 16 + g * 4;
      int b = row >> 10, t = row & 1023;
      #pragma unroll
      for (int nf = 0; nf < 4; ++nf) {
        int col = bn + wc * 64 + nf * 16 + lr;
        int cc = col & 1023;
        int h = cc >> 6, d = cc & 63;
        float bs = bias[col];
        union { ushort u[4]; uint2 v; } pk4;
        #pragma unroll
        for (int reg = 0; reg < 4; ++reg) pk4.u[reg] = f2bf(acc[mf][nf][reg] + bs);
        *(uint2*)&vb[((size_t)(b * 16 + h) * 64 + d) * T_ + t] = pk4.v;
      }
    }
    return;
  }

  ushort* dst = nullptr; float scl = 1.f;
  if (EPI == 3) {
    int sec = bn >> 10;
    dst = (sec == 0) ? qb : kb;
    scl = (sec == 0) ? 0.125f : 1.f;
  }
  #pragma unroll
  for (int mf = 0; mf < 4; ++mf)
    #pragma unroll
    for (int reg = 0; reg < 4; ++reg) {
      int row = bm + wr * 64 + mf * 16 + g * 4 + reg;
      #pragma unroll
      for (int nf = 0; nf < 4; ++nf) {
        int col = bn + wc * 64 + nf * 16 + lr;
        float v = acc[mf][nf][reg];
        if (EPI != 4) v += bias[col];
        if (EPI == 1) {
          outf[(size_t)row * N + col] = v + res[(size_t)row * N + col];
        } else if (EPI == 2) {
          float gl = 0.5f * v * (1.f + erff(v * 0.70710678118654752f));
          outh[(size_t)row * N + col] = f2bf(gl);
        } else if (EPI == 4) {
          outh[((size_t)sk * M_ + row) * N + col] = f2bf(v);
        } else {
          int b = row >> 10, t = row & 1023;
          int cc = col & 1023;
          int h = cc >> 6, d = cc & 63;
          dst[((size_t)(b * 16 + h) * T_ + t) * 64 + d] = f2bf(v * scl);
        }
      }
    }
}

__global__ __launch_bounds__(256, 5)
void gbt2_qkv(const ushort* A, const ushort* W, const float* bias,
              ushort* qb, ushort* kb, ushort* vtb) {
  gbt2_body<3>(A, W, bias, nullptr, nullptr, nullptr, qb, kb, vtb, 3 * E_, E_, E_, 24);
}
__global__ __launch_bounds__(256, 5)
void gbt2_fc(const ushort* A, const ushort* W, const float* bias, ushort* outh) {
  gbt2_body<2>(A, W, bias, nullptr, nullptr, outh, nullptr, nullptr, nullptr, 4 * E_, E_, E_, 32);
}
__global__ __launch_bounds__(256, 5)
void gbt2_sk(const ushort* A, const ushort* W, ushort* pbh) {
  gbt2_body<4>(A, W, nullptr, nullptr, nullptr, pbh, nullptr, nullptr, nullptr, E_, E_, 4 * E_, 8);
}
__global__ __launch_bounds__(256, 5)
void gbt2_proj(const ushort* A, const ushort* W, const float* bias,
               const float* res, float* outf) {
  gbt2_body<1>(A, W, bias, res, outf, nullptr, nullptr, nullptr, nullptr, E_, E_, E_, 8);
}

// ---------------- attention: 4-wave block, K/V LDS-shared, swapped-QK^T ------------
static __device__ __forceinline__ void sm_step(
    f32x4 (&s)[4], float& m, float& l, f32x4 (&acc)[4], bf16x8 (&ap)[2],
    int qrow, int kbase0, bool diag, int g) {
  if (diag) {
    #pragma unroll
    for (int nf = 0; nf < 4; ++nf)
      #pragma unroll
      for (int reg = 0; reg < 4; ++reg)
        if (kbase0 + nf * 16 + g * 4 + reg > qrow) s[nf][reg] = -INFINITY;
  }
  float pmax = s[0][0];
  #pragma unroll
  for (int nf = 0; nf < 4; ++nf)
    #pragma unroll
    for (int reg = 0; reg < 4; ++reg) pmax = fmaxf(pmax, s[nf][reg]);
  pmax = fmaxf(pmax, __shfl_xor(pmax, 16));
  pmax = fmaxf(pmax, __shfl_xor(pmax, 32));
  if (__any(pmax > m + 8.f)) {
    float mn = fmaxf(m, pmax);
    float corr = __expf(m - mn);
    m = mn; l *= corr;
    #pragma unroll
    for (int reg = 0; reg < 4; ++reg) {
      float cc = __shfl(corr, g * 4 + reg);
      #pragma unroll
      for (int nfd = 0; nfd < 4; ++nfd) acc[nfd][reg] *= cc;
    }
  }
  float ps = 0.f;
  union { bf16x8 v[2]; ushort u[16]; } pk;
  #pragma unroll
  for (int nf = 0; nf < 4; ++nf)
    #pragma unroll
    for (int reg = 0; reg < 4; ++reg) {
      float pv = __expf(s[nf][reg] - m);
      ps += pv;
      pk.u[nf * 4 + reg] = f2bf(pv);
    }
  ps += __shfl_xor(ps, 16);
  ps += __shfl_xor(ps, 32);
  l += ps;
  ap[0] = pk.v[0];
  ap[1] = pk.v[1];
}

__global__ __launch_bounds__(256) void attn4_k(const ushort* __restrict__ Qg,
    const ushort* __restrict__ Kg, const ushort* __restrict__ Vg,
    ushort* __restrict__ y) {
  __shared__ __align__(16) ushort KL[2][4096];
  __shared__ __align__(16) ushort VL[2][4096];
  int bh = blockIdx.x;
  int qt = blockIdx.y;
  int tid = threadIdx.x, w = tid >> 6, lane = tid & 63;
  int g = lane >> 4, lr = lane & 15;
  int sl8 = lane >> 3, sc = lane & 7;
  int cg8 = (sc ^ sl8) * 8;
  int qbase = qt * 128 + w * 32;

  const ushort* kbase = Kg + (size_t)bh * T_ * 64;
  const ushort* vbase = Vg + (size_t)bh * 64 * T_;

  bf16x8 aq[2][2];
  #pragma unroll
  for (int st = 0; st < 2; ++st) {
    const ushort* qp = Qg + ((size_t)bh * T_ + qbase + st * 16 + lr) * 64;
    aq[st][0] = __builtin_bit_cast(bf16x8, *(const s16x8*)(qp + g * 8));
    aq[st][1] = __builtin_bit_cast(bf16x8, *(const s16x8*)(qp + 32 + g * 8));
  }

  f32x4 accO[2][4] = {};
  float m0 = -INFINITY, m1 = -INFINITY, l0 = 0.f, l1 = 0.f;

  int nkt_blk = 2 * qt + 2;
  int nw = ((qbase + 31) >> 6) + 1;
  int r8 = w * 8 + sl8;

  #define STG_KV(buf, kt) do { \
    _Pragma("unroll") \
    for (int j_ = 0; j_ < 2; ++j_) { \
      GLDS(kbase + (size_t)((kt) * 64 + j_ * 32 + r8) * 64 + cg8, &KL[buf][(j_ * 32 + w * 8) * 64]); \
      GLDS(vbase + (size_t)(j_ * 32 + r8) * T_ + (kt) * 64 + cg8, &VL[buf][(j_ * 32 + w * 8) * 64]); \
    } \
  } while (0)

  STG_KV(0, 0);
  __syncthreads();

  for (int kt = 0; kt < nkt_blk; ++kt) {
    int cbuf = kt & 1;
    if (kt + 1 < nkt_blk) STG_KV(cbuf ^ 1, kt + 1);

    if (kt < nw) {
      bool diag = (kt == nw - 1);
      f32x4 s0[4] = {}, s1[4] = {};
      #pragma unroll
      for (int ks = 0; ks < 2; ++ks)
        #pragma unroll
        for (int nf = 0; nf < 4; ++nf) {
          int row = nf * 16 + lr;
          bf16x8 ak = __builtin_bit_cast(bf16x8,
              *(const s16x8*)&KL[cbuf][row * 64 + (((ks * 4 + g) ^ (lr & 7)) * 8)]);
          s0[nf] = __builtin_amdgcn_mfma_f32_16x16x32_bf16(ak, aq[0][ks], s0[nf], 0, 0, 0);
          s1[nf] = __builtin_amdgcn_mfma_f32_16x16x32_bf16(ak, aq[1][ks], s1[nf], 0, 0, 0);
        }

      bf16x8 ap0[2], ap1[2];
      sm_step(s0, m0, l0, accO[0], ap0, qbase + 0 * 16 + lr, kt * 64, diag, g);
      sm_step(s1, m1, l1, accO[1], ap1, qbase + 1 * 16 + lr, kt * 64, diag, g);

      #pragma unroll
      for (int ks = 0; ks < 2; ++ks)
        #pragma unroll
        for (int nfd = 0; nfd < 4; ++nfd) {
          int row = nfd * 16 + lr;
          int c1 = ks * 4 + (g >> 1), sub = (g & 1) * 4;
          uint2 lo = *(const uint2*)&VL[cbuf][row * 64 + ((c1 ^ (lr & 7)) * 8 + sub)];
          uint2 hi = *(const uint2*)&VL[cbuf][row * 64 + (((c1 + 2) ^ (lr & 7)) * 8 + sub)];
          union { uint4 u; bf16x8 v; } bb;
          bb.u = make_uint4(lo.x, lo.y, hi.x, hi.y);
          accO[0][nfd] = __builtin_amdgcn_mfma_f32_16x16x32_bf16(ap0[ks], bb.v, accO[0][nfd], 0, 0, 0);
          accO[1][nfd] = __builtin_amdgcn_mfma_f32_16x16x32_bf16(ap1[ks], bb.v, accO[1][nfd], 0, 0, 0);
        }
    }
    __syncthreads();
  }

  int b = bh >> 4, h = bh & 15;
  float li0 = 1.f / l0, li1 = 1.f / l1;
  #pragma unroll
  for (int st = 0; st < 2; ++st) {
    float lsrc = (st == 0) ? li0 : li1;
    #pragma unroll
    for (int reg = 0; reg < 4; ++reg) {
      float inv = __shfl(lsrc, g * 4 + reg);
      size_t row = (size_t)b * T_ + qbase + st * 16 + g * 4 + reg;
      #pragma unroll
      for (int nfd = 0; nfd < 4; ++nfd)
        y[row * E_ + h * 64 + nfd * 16 + lr] = f2bf(accO[st][nfd][reg] * inv);
    }
  }
  #undef STG_KV
}

// ---------------- orchestration ----------------
extern "C" void kernel_launch(void* const* d_in, const int* in_sizes, int n_in,
                              void* d_out, int out_size, void* d_ws, size_t ws_size,
                              hipStream_t stream) {
  const int*   idx   = (const int*)  d_in[0];
  const float* wte   = (const float*)d_in[1];
  const float* wpe   = (const float*)d_in[2];
  const float* ln1w  = (const float*)d_in[3];
  const float* ln1b  = (const float*)d_in[4];
  const float* attnw = (const float*)d_in[5];
  const float* attnb = (const float*)d_in[6];
  const float* projw = (const float*)d_in[7];
  const float* projb = (const float*)d_in[8];
  const float* ln2w  = (const float*)d_in[9];
  const float* ln2b  = (const float*)d_in[10];
  const float* fcw   = (const float*)d_in[11];
  const float* fcb   = (const float*)d_in[12];
  const float* fc2w  = (const float*)d_in[13];
  const float* fc2b  = (const float*)d_in[14];
  const float* lnfw  = (const float*)d_in[15];
  const float* lnfb  = (const float*)d_in[16];
  const float* lmw   = (const float*)d_in[17];
  float* out = (float*)d_out;

  char* p = (char*)d_ws;
  auto take = [&](size_t bytes) { char* r = p; p += (bytes + 255) & ~(size_t)255; return r; };
  ushort* wb_attn = (ushort*)take((size_t)L_ * 3 * E_ * E_ * 2);
  ushort* wb_proj = (ushort*)take((size_t)L_ * E_ * E_ * 2);
  ushort* wb_fc   = (ushort*)take((size_t)L_ * 4 * E_ * E_ * 2);
  ushort* wb_fc2  = (ushort*)take((size_t)L_ * E_ * 4 * E_ * 2);
  ushort* wb_lm   = (ushort*)take((size_t)V_ * E_ * 2);
  float*  x       = (float*) take((size_t)M_ * E_ * 4);
  ushort* hbuf    = (ushort*)take((size_t)M_ * E_ * 2);
  ushort* qb      = (ushort*)take((size_t)B_ * 16 * T_ * 64 * 2);
  ushort* kbuf    = (ushort*)take((size_t)B_ * 16 * T_ * 64 * 2);
  ushort* vtb     = (ushort*)take((size_t)B_ * 16 * T_ * 64 * 2);
  ushort* ybuf    = (ushort*)take((size_t)M_ * E_ * 2);
  ushort* mlp     = (ushort*)take((size_t)M_ * 4 * E_ * 2);
  ushort* pbh     = (ushort*)take((size_t)4 * M_ * E_ * 2);

  start_k<<<65152 + M_, 256, 0, stream>>>(attnw, projw, fcw, fc2w, lmw,
                                          wb_attn, wb_proj, wb_fc, wb_fc2, wb_lm,
                                          idx, wte, wpe, ln1w, ln1b, x, hbuf);

  for (int l = 0; l < L_; ++l) {
    gbt2_qkv<<<24 * 32, 256, 0, stream>>>(
        hbuf, wb_attn + (size_t)l * 3 * E_ * E_, attnb + l * 3 * E_, qb, kbuf, vtb);
    attn4_k<<<dim3(B_ * 16, T_ / 128), 256, 0, stream>>>(qb, kbuf, vtb, ybuf);
    gbt2_proj<<<8 * 32, 256, 0, stream>>>(
        ybuf, wb_proj + (size_t)l * E_ * E_, projb + l * E_, x, x);
    ln_k<<<M_, 256, 0, stream>>>(x, ln2w + l * E_, ln2b + l * E_, hbuf);
    gbt2_fc<<<32 * 32, 256, 0, stream>>>(
        hbuf, wb_fc + (size_t)l * 4 * E_ * E_, fcb + l * 4 * E_, mlp);
    gbt2_sk<<<4 * 8 * 32, 256, 0, stream>>>(mlp, wb_fc2 + (size_t)l * E_ * 4 * E_, pbh);
    if (l < L_ - 1)
      redln_k<<<M_, 256, 0, stream>>>(pbh, fc2b + l * E_, x,
                                      ln1w + (l + 1) * E_, ln1b + (l + 1) * E_, hbuf);
    else
      redln_k<<<M_, 256, 0, stream>>>(pbh, fc2b + l * E_, x, lnfw, lnfb, hbuf);
  }
  gemm8_lm<<<(V_ / 256) * (M_ / 256), 512, 0, stream>>>(hbuf, wb_lm, out);
}

// Round 22
// 2187.488 us; speedup vs baseline: 2.0454x; 2.0454x over previous
//
#include <hip/hip_runtime.h>

typedef __bf16 bf16x8 __attribute__((ext_vector_type(8)));
typedef float  f32x4  __attribute__((ext_vector_type(4)));
typedef short  s16x8  __attribute__((ext_vector_type(8)));
typedef unsigned int u32;
#define AS1 __attribute__((address_space(1)))
#define AS3 __attribute__((address_space(3)))

#define E_ 1024
#define T_ 1024
#define B_ 4
#define L_ 8
#define V_ 32000
#define M_ (B_*T_)   /* 4096 rows */

static __device__ __forceinline__ ushort f2bf(float f) {
  return __builtin_bit_cast(ushort, (__bf16)f);
}
static __device__ __forceinline__ float bf2f(ushort u) {
  u32 t = (u32)u << 16;
  return __builtin_bit_cast(float, t);
}

// inline-asm LDS read (compiler-invisible scheduling; waits are manual)
static __device__ __forceinline__ bf16x8 dsr(const ushort* p) {
  u32 a = (u32)(size_t)(const AS3 ushort*)p;
  bf16x8 d;
  asm volatile("ds_read_b128 %0, %1" : "=v"(d) : "v"(a));
  return d;
}

// ---------------- LN core ----------------
static __device__ __forceinline__ void ln_core(float4 v, int t,
    const float* __restrict__ w, const float* __restrict__ b,
    ushort* __restrict__ out, size_t row) {
  float s  = v.x + v.y + v.z + v.w;
  float s2 = v.x*v.x + v.y*v.y + v.z*v.z + v.w*v.w;
  #pragma unroll
  for (int o = 32; o > 0; o >>= 1) { s += __shfl_down(s, o); s2 += __shfl_down(s2, o); }
  __shared__ float sh[8];
  int wv = t >> 6;
  if ((t & 63) == 0) { sh[wv] = s; sh[4 + wv] = s2; }
  __syncthreads();
  s  = sh[0] + sh[1] + sh[2] + sh[3];
  s2 = sh[4] + sh[5] + sh[6] + sh[7];
  float mean = s * (1.f / E_);
  float var  = s2 * (1.f / E_) - mean * mean;
  float inv  = rsqrtf(var + 1e-5f);
  float4 wv4 = ((const float4*)w)[t];
  float4 bv4 = ((const float4*)b)[t];
  ushort* op = out + row * E_ + t * 4;
  op[0] = f2bf((v.x - mean) * inv * wv4.x + bv4.x);
  op[1] = f2bf((v.y - mean) * inv * wv4.y + bv4.y);
  op[2] = f2bf((v.z - mean) * inv * wv4.z + bv4.z);
  op[3] = f2bf((v.w - mean) * inv * wv4.w + bv4.w);
}

// ---------------- startup: weight casts (5 tensors) + embed+ln1, 1 dispatch ------
__global__ __launch_bounds__(256) void start_k(
    const float* __restrict__ a0, const float* __restrict__ a1,
    const float* __restrict__ a2, const float* __restrict__ a3,
    const float* __restrict__ a4,
    ushort* __restrict__ o0, ushort* __restrict__ o1, ushort* __restrict__ o2,
    ushort* __restrict__ o3, ushort* __restrict__ o4,
    const int* __restrict__ idx, const float* __restrict__ wte,
    const float* __restrict__ wpe, const float* __restrict__ lw,
    const float* __restrict__ lb, float* __restrict__ x,
    ushort* __restrict__ hout) {
  int bid = blockIdx.x;
  if (bid >= 65152) {                 // embed + ln1(layer0): 4096 blocks
    int row = bid - 65152;
    int tok = idx[row];
    int t = row & (T_ - 1);
    int c = threadIdx.x;
    float4 a = ((const float4*)(wte + (size_t)tok * E_))[c];
    float4 p = ((const float4*)(wpe + (size_t)t * E_))[c];
    float4 v; v.x = a.x + p.x; v.y = a.y + p.y; v.z = a.z + p.z; v.w = a.w + p.w;
    ((float4*)(x + (size_t)row * E_))[c] = v;
    ln_core(v, c, lw, lb, hout, (size_t)row);
    return;
  }
  const float* in; ushort* out; int base;
  if (bid < 12288)      { in = a0; out = o0; base = bid; }
  else if (bid < 16384) { in = a1; out = o1; base = bid - 12288; }
  else if (bid < 32768) { in = a2; out = o2; base = bid - 16384; }
  else if (bid < 49152) { in = a3; out = o3; base = bid - 32768; }
  else                  { in = a4; out = o4; base = bid - 49152; }
  size_t i = ((size_t)base * 256 + threadIdx.x) * 8;
  float4 a = *(const float4*)(in + i);
  float4 b = *(const float4*)(in + i + 4);
  float v[8] = {a.x, a.y, a.z, a.w, b.x, b.y, b.z, b.w};
  union { s16x8 v; ushort u[8]; } pk;
  #pragma unroll
  for (int j = 0; j < 8; ++j) pk.u[j] = f2bf(v[j]);
  *(s16x8*)(out + i) = pk.v;
}

// ---------------- layernorm (f32 in, bf16 out) ----------------
__global__ __launch_bounds__(256) void ln_k(const float* __restrict__ x,
    const float* __restrict__ w, const float* __restrict__ b,
    ushort* __restrict__ out) {
  int row = blockIdx.x;
  int t = threadIdx.x;
  float4 v = ((const float4*)(x + (size_t)row * E_))[t];
  ln_core(v, t, w, b, out, (size_t)row);
}

// ---------------- split-K reduce (bf16 partials) + bias + residual + LN ----------
__global__ __launch_bounds__(256) void redln_k(const ushort* __restrict__ p,
    const float* __restrict__ bias, float* __restrict__ x,
    const float* __restrict__ w, const float* __restrict__ b,
    ushort* __restrict__ out) {
  int row = blockIdx.x;
  int t = threadIdx.x;
  float4 v = ((const float4*)(x + (size_t)row * E_))[t];
  float4 bb = ((const float4*)bias)[t];
  v.x += bb.x; v.y += bb.y; v.z += bb.z; v.w += bb.w;
  #pragma unroll
  for (int sk = 0; sk < 4; ++sk) {
    const ushort* q = p + ((size_t)sk * M_ + row) * E_ + t * 4;
    v.x += bf2f(q[0]); v.y += bf2f(q[1]); v.z += bf2f(q[2]); v.w += bf2f(q[3]);
  }
  ((float4*)(x + (size_t)row * E_))[t] = v;
  ln_core(v, t, w, b, out, (size_t)row);
}

// ======================================================================
// gemm8 (lm_head only): 256x256, m201-style 8-phase schedule (r16, proven).
// ======================================================================
template<int BUF, int MH, int NH, int RA, int RB, int VM, typename F>
static __device__ __forceinline__ void ph8(
    const ushort* AL, const ushort* BL,
    bf16x8 (&av)[2][4][2], bf16x8 (&bv)[2][2][2],
    int arow, int brow, int ca0, int ca1, f32x4 (&acc)[8][4], F&& stage) {
  if (RA) {
    #pragma unroll
    for (int mfi = 0; mfi < 4; ++mfi) {
      av[MH][mfi][0] = dsr(&AL[(BUF*2+MH)*8192 + arow + mfi*1024 + ca0]);
      av[MH][mfi][1] = dsr(&AL[(BUF*2+MH)*8192 + arow + mfi*1024 + ca1]);
    }
  }
  if (RB) {
    #pragma unroll
    for (int nfi = 0; nfi < 2; ++nfi) {
      bv[NH][nfi][0] = dsr(&BL[(BUF*2+NH)*8192 + brow + nfi*1024 + ca0]);
      bv[NH][nfi][1] = dsr(&BL[(BUF*2+NH)*8192 + brow + nfi*1024 + ca1]);
    }
  }
  stage();
  __builtin_amdgcn_s_barrier();
  asm volatile("s_waitcnt lgkmcnt(0)");
  __builtin_amdgcn_sched_barrier(0);
  __builtin_amdgcn_s_setprio(1);
  #pragma unroll
  for (int ks = 0; ks < 2; ++ks)
    #pragma unroll
    for (int mfi = 0; mfi < 4; ++mfi)
      #pragma unroll
      for (int nfi = 0; nfi < 2; ++nfi)
        acc[MH*4+mfi][NH*2+nfi] = __builtin_amdgcn_mfma_f32_16x16x32_bf16(
            av[MH][mfi][ks], bv[NH][nfi][ks], acc[MH*4+mfi][NH*2+nfi], 0, 0, 0);
  __builtin_amdgcn_s_setprio(0);
  if (VM) asm volatile("s_waitcnt vmcnt(4)");
  __builtin_amdgcn_s_barrier();
  __builtin_amdgcn_sched_barrier(0);
}

#define GLDS(src, dst) __builtin_amdgcn_global_load_lds((const AS1 u32*)(src), (AS3 u32*)(dst), 16, 0, 0)
#define STAGE_A(b, s, t) do { \
  GLDS(ap##s##_0 + (size_t)(t)*64, &AL[((b)*2+(s))*8192 + w*512]); \
  GLDS(ap##s##_1 + (size_t)(t)*64, &AL[((b)*2+(s))*8192 + 4096 + w*512]); } while(0)
#define STAGE_B(b, s, t) do { \
  GLDS(bp##s##_0 + (size_t)(t)*64, &BL[((b)*2+(s))*8192 + w*512]); \
  GLDS(bp##s##_1 + (size_t)(t)*64, &BL[((b)*2+(s))*8192 + 4096 + w*512]); } while(0)

__global__ __launch_bounds__(512, 2)
void gemm8_lm(const ushort* __restrict__ A, const ushort* __restrict__ W,
              float* __restrict__ outf) {
  const int N = V_, K = E_, Kst = E_;
  __shared__ __align__(16) ushort AL[32768];
  __shared__ __align__(16) ushort BL[32768];
  int id  = blockIdx.x;
  int nwg = gridDim.x;
  int swz = (id & 7) * (nwg >> 3) + (id >> 3);
  int bx = swz >> 4, by = swz & 15;
  int bm = by * 256, bn = bx * 256;
  int tid = threadIdx.x;
  int w = tid >> 6, lane = tid & 63;
  int wm = w >> 2, wn = w & 3;
  int g = lane >> 4, lr = lane & 15;
  int sl8 = lane >> 3, sc = lane & 7;
  int cg8 = (sc ^ sl8) * 8;

  int r0 = w * 8 + sl8;
  const ushort* ap0_0 = A + (size_t)(bm +       0 + r0) * Kst + cg8;
  const ushort* ap0_1 = A + (size_t)(bm + 128 + 0 + r0) * Kst + cg8;
  const ushort* ap1_0 = A + (size_t)(bm +      64 + r0) * Kst + cg8;
  const ushort* ap1_1 = A + (size_t)(bm + 128 + 64 + r0) * Kst + cg8;
  int sr0 = r0, sr1 = 64 + r0;
  const ushort* bp0_0 = W + (size_t)(bn + (sr0 >> 5) * 64 +  0 + (sr0 & 31)) * Kst + cg8;
  const ushort* bp0_1 = W + (size_t)(bn + (sr1 >> 5) * 64 +  0 + (sr1 & 31)) * Kst + cg8;
  const ushort* bp1_0 = W + (size_t)(bn + (sr0 >> 5) * 64 + 32 + (sr0 & 31)) * Kst + cg8;
  const ushort* bp1_1 = W + (size_t)(bn + (sr1 >> 5) * 64 + 32 + (sr1 & 31)) * Kst + cg8;

  int NT = K >> 6;
  int NITER = NT >> 1;
  int arow = (wm * 64 + lr) * 64;
  int brow = (wn * 32 + lr) * 64;
  int ca0 = ((0 + g) ^ (lr & 7)) * 8;
  int ca1 = ((4 + g) ^ (lr & 7)) * 8;
  f32x4 acc[8][4] = {};
  bf16x8 av[2][4][2], bv[2][2][2];

  STAGE_A(0, 0, 0); STAGE_A(0, 1, 0); STAGE_B(0, 0, 0); STAGE_B(0, 1, 0);
  STAGE_A(1, 0, 1); STAGE_B(1, 0, 1);
  asm volatile("s_waitcnt vmcnt(0)" ::: "memory");
  __builtin_amdgcn_s_barrier();
  __builtin_amdgcn_sched_barrier(0);

  for (int i = 0; i < NITER; ++i) {
    int t1 = 2 * i + 1;
    int t2 = 2 * i + 2; if (t2 > NT - 1) t2 = NT - 1;
    int t3 = 2 * i + 3; if (t3 > NT - 1) t3 = NT - 1;
    ph8<0,0,0,1,1,0>(AL, BL, av, bv, arow, brow, ca0, ca1, acc, [&]{ STAGE_A(1, 1, t1); });
    ph8<0,0,1,0,1,0>(AL, BL, av, bv, arow, brow, ca0, ca1, acc, [&]{ STAGE_B(1, 1, t1); });
    ph8<0,1,1,1,0,0>(AL, BL, av, bv, arow, brow, ca0, ca1, acc, [&]{ STAGE_A(0, 0, t2); });
    ph8<0,1,0,0,0,1>(AL, BL, av, bv, arow, brow, ca0, ca1, acc, [&]{ STAGE_B(0, 0, t2); });
    ph8<1,0,0,1,1,0>(AL, BL, av, bv, arow, brow, ca0, ca1, acc, [&]{ STAGE_A(0, 1, t2); });
    ph8<1,0,1,0,1,0>(AL, BL, av, bv, arow, brow, ca0, ca1, acc, [&]{ STAGE_B(0, 1, t2); });
    ph8<1,1,1,1,0,0>(AL, BL, av, bv, arow, brow, ca0, ca1, acc, [&]{ STAGE_A(1, 0, t3); });
    ph8<1,1,0,0,0,1>(AL, BL, av, bv, arow, brow, ca0, ca1, acc, [&]{ STAGE_B(1, 0, t3); });
  }

  #pragma unroll
  for (int mf = 0; mf < 8; ++mf)
    #pragma unroll
    for (int reg = 0; reg < 4; ++reg) {
      int row = bm + wm * 128 + mf * 16 + g * 4 + reg;
      #pragma unroll
      for (int nf = 0; nf < 4; ++nf) {
        int col = bn + wn * 64 + nf * 16 + lr;
        outf[(size_t)row * N + col] = acc[mf][nf][reg];
      }
    }
}

// ======================================================================
// gbt2: 128x128, BK=64, conflict-free swizzled LDS, 32KB, 4 blk/CU (proven).
// EPI 1: outf=acc+bias+res | 2: outh=gelu | 3: qkv scatter (V transposed)
// EPI 4: split-K bf16 partials (Kst=4096, K=1024)
// ======================================================================
template<int EPI>
static __device__ __forceinline__
void gbt2_body(const ushort* __restrict__ A, const ushort* __restrict__ W,
               const float* __restrict__ bias, const float* __restrict__ res,
               float* __restrict__ outf, ushort* __restrict__ outh,
               ushort* __restrict__ qb, ushort* __restrict__ kb, ushort* __restrict__ vb,
               int N, int K, int Kst, int gx) {
  __shared__ __align__(16) ushort As[128 * 64];
  __shared__ __align__(16) ushort Ws[128 * 64];
  int id  = blockIdx.x;
  int nwg = gridDim.x;
  int swz = (id & 7) * (nwg >> 3) + (id >> 3);
  int sk = 0;
  if (EPI == 4) { sk = swz >> 8; swz &= 255; }
  int bx = swz / 32, by = swz & 31;
  int bm = by * 128, bn = bx * 128;
  int tid  = threadIdx.x;
  int wave = tid >> 6, lane = tid & 63;
  int wr = wave >> 1, wc = wave & 1;
  int g  = lane >> 4, lr = lane & 15;
  int sl8 = lane >> 3, sc = lane & 7;
  int cg8 = (sc ^ sl8) * 8;
  int r0 = wave * 8 + sl8;

  const ushort* ap = A + (size_t)sk * 1024 + (size_t)(bm + r0) * Kst + cg8;
  const ushort* wp = W + (size_t)sk * 1024 + (size_t)(bn + r0) * Kst + cg8;
  f32x4 acc[4][4] = {};

  for (int k0 = 0; k0 < K; k0 += 64) {
    #pragma unroll
    for (int j = 0; j < 4; ++j) {
      GLDS(ap + (size_t)(j * 32) * Kst + k0, &As[(wave * 8 + j * 32) * 64]);
      GLDS(wp + (size_t)(j * 32) * Kst + k0, &Ws[(wave * 8 + j * 32) * 64]);
    }
    __syncthreads();
    #pragma unroll
    for (int ks = 0; ks < 2; ++ks) {
      int ca = ((ks * 4 + g) ^ (lr & 7)) * 8;
      bf16x8 af[4], bfr[4];
      #pragma unroll
      for (int f = 0; f < 4; ++f) {
        af[f]  = __builtin_bit_cast(bf16x8, *(const s16x8*)&As[(wr * 64 + f * 16 + lr) * 64 + ca]);
        bfr[f] = __builtin_bit_cast(bf16x8, *(const s16x8*)&Ws[(wc * 64 + f * 16 + lr) * 64 + ca]);
      }
      #pragma unroll
      for (int mf = 0; mf < 4; ++mf)
        #pragma unroll
        for (int nf = 0; nf < 4; ++nf)
          acc[mf][nf] = __builtin_amdgcn_mfma_f32_16x16x32_bf16(af[mf], bfr[nf], acc[mf][nf], 0, 0, 0);
    }
    __syncthreads();
  }

  if (EPI == 3 && (bn >> 10) == 2) {
    #pragma unroll
    for (int mf = 0; mf < 4; ++mf) {
      int row = bm + wr * 64 + mf * 16 + g * 4;
      int b = row >> 10, t = row & 1023;
      #pragma unroll
      for (int nf = 0; nf < 4; ++nf) {
        int col = bn + wc * 64 + nf * 16 + lr;
        int cc = col & 1023;
        int h = cc >> 6, d = cc & 63;
        float bs = bias[col];
        union { ushort u[4]; uint2 v; } pk4;
        #pragma unroll
        for (int reg = 0; reg < 4; ++reg) pk4.u[reg] = f2bf(acc[mf][nf][reg] + bs);
        *(uint2*)&vb[((size_t)(b * 16 + h) * 64 + d) * T_ + t] = pk4.v;
      }
    }
    return;
  }

  ushort* dst = nullptr; float scl = 1.f;
  if (EPI == 3) {
    int sec = bn >> 10;
    dst = (sec == 0) ? qb : kb;
    scl = (sec == 0) ? 0.125f : 1.f;
  }
  #pragma unroll
  for (int mf = 0; mf < 4; ++mf)
    #pragma unroll
    for (int reg = 0; reg < 4; ++reg) {
      int row = bm + wr * 64 + mf * 16 + g * 4 + reg;
      #pragma unroll
      for (int nf = 0; nf < 4; ++nf) {
        int col = bn + wc * 64 + nf * 16 + lr;
        float v = acc[mf][nf][reg];
        if (EPI != 4) v += bias[col];
        if (EPI == 1) {
          outf[(size_t)row * N + col] = v + res[(size_t)row * N + col];
        } else if (EPI == 2) {
          float gl = 0.5f * v * (1.f + erff(v * 0.70710678118654752f));
          outh[(size_t)row * N + col] = f2bf(gl);
        } else if (EPI == 4) {
          outh[((size_t)sk * M_ + row) * N + col] = f2bf(v);
        } else {
          int b = row >> 10, t = row & 1023;
          int cc = col & 1023;
          int h = cc >> 6, d = cc & 63;
          dst[((size_t)(b * 16 + h) * T_ + t) * 64 + d] = f2bf(v * scl);
        }
      }
    }
}

__global__ __launch_bounds__(256, 4)
void gbt2_qkv(const ushort* A, const ushort* W, const float* bias,
              ushort* qb, ushort* kb, ushort* vtb) {
  gbt2_body<3>(A, W, bias, nullptr, nullptr, nullptr, qb, kb, vtb, 3 * E_, E_, E_, 24);
}
__global__ __launch_bounds__(256, 4)
void gbt2_fc(const ushort* A, const ushort* W, const float* bias, ushort* outh) {
  gbt2_body<2>(A, W, bias, nullptr, nullptr, outh, nullptr, nullptr, nullptr, 4 * E_, E_, E_, 32);
}
__global__ __launch_bounds__(256, 4)
void gbt2_sk(const ushort* A, const ushort* W, ushort* pbh) {
  gbt2_body<4>(A, W, nullptr, nullptr, nullptr, pbh, nullptr, nullptr, nullptr, E_, E_, 4 * E_, 8);
}
__global__ __launch_bounds__(256, 4)
void gbt2_proj(const ushort* A, const ushort* W, const float* bias,
               const float* res, float* outf) {
  gbt2_body<1>(A, W, bias, res, outf, nullptr, nullptr, nullptr, nullptr, E_, E_, E_, 8);
}

// ---------------- attention: 4-wave block, K/V LDS-shared, swapped-QK^T ------------
static __device__ __forceinline__ void sm_step(
    f32x4 (&s)[4], float& m, float& l, f32x4 (&acc)[4], bf16x8 (&ap)[2],
    int qrow, int kbase0, bool diag, int g) {
  if (diag) {
    #pragma unroll
    for (int nf = 0; nf < 4; ++nf)
      #pragma unroll
      for (int reg = 0; reg < 4; ++reg)
        if (kbase0 + nf * 16 + g * 4 + reg > qrow) s[nf][reg] = -INFINITY;
  }
  float pmax = s[0][0];
  #pragma unroll
  for (int nf = 0; nf < 4; ++nf)
    #pragma unroll
    for (int reg = 0; reg < 4; ++reg) pmax = fmaxf(pmax, s[nf][reg]);
  pmax = fmaxf(pmax, __shfl_xor(pmax, 16));
  pmax = fmaxf(pmax, __shfl_xor(pmax, 32));
  if (__any(pmax > m + 8.f)) {
    float mn = fmaxf(m, pmax);
    float corr = __expf(m - mn);
    m = mn; l *= corr;
    #pragma unroll
    for (int reg = 0; reg < 4; ++reg) {
      float cc = __shfl(corr, g * 4 + reg);
      #pragma unroll
      for (int nfd = 0; nfd < 4; ++nfd) acc[nfd][reg] *= cc;
    }
  }
  float ps = 0.f;
  union { bf16x8 v[2]; ushort u[16]; } pk;
  #pragma unroll
  for (int nf = 0; nf < 4; ++nf)
    #pragma unroll
    for (int reg = 0; reg < 4; ++reg) {
      float pv = __expf(s[nf][reg] - m);
      ps += pv;
      pk.u[nf * 4 + reg] = f2bf(pv);
    }
  ps += __shfl_xor(ps, 16);
  ps += __shfl_xor(ps, 32);
  l += ps;
  ap[0] = pk.v[0];
  ap[1] = pk.v[1];
}

__global__ __launch_bounds__(256) void attn4_k(const ushort* __restrict__ Qg,
    const ushort* __restrict__ Kg, const ushort* __restrict__ Vg,
    ushort* __restrict__ y) {
  __shared__ __align__(16) ushort KL[2][4096];
  __shared__ __align__(16) ushort VL[2][4096];
  int bh = blockIdx.x;
  int qt = blockIdx.y;
  int tid = threadIdx.x, w = tid >> 6, lane = tid & 63;
  int g = lane >> 4, lr = lane & 15;
  int sl8 = lane >> 3, sc = lane & 7;
  int cg8 = (sc ^ sl8) * 8;
  int qbase = qt * 128 + w * 32;

  const ushort* kbase = Kg + (size_t)bh * T_ * 64;
  const ushort* vbase = Vg + (size_t)bh * 64 * T_;

  bf16x8 aq[2][2];
  #pragma unroll
  for (int st = 0; st < 2; ++st) {
    const ushort* qp = Qg + ((size_t)bh * T_ + qbase + st * 16 + lr) * 64;
    aq[st][0] = __builtin_bit_cast(bf16x8, *(const s16x8*)(qp + g * 8));
    aq[st][1] = __builtin_bit_cast(bf16x8, *(const s16x8*)(qp + 32 + g * 8));
  }

  f32x4 accO[2][4] = {};
  float m0 = -INFINITY, m1 = -INFINITY, l0 = 0.f, l1 = 0.f;

  int nkt_blk = 2 * qt + 2;
  int nw = ((qbase + 31) >> 6) + 1;
  int r8 = w * 8 + sl8;

  #define STG_KV(buf, kt) do { \
    _Pragma("unroll") \
    for (int j_ = 0; j_ < 2; ++j_) { \
      GLDS(kbase + (size_t)((kt) * 64 + j_ * 32 + r8) * 64 + cg8, &KL[buf][(j_ * 32 + w * 8) * 64]); \
      GLDS(vbase + (size_t)(j_ * 32 + r8) * T_ + (kt) * 64 + cg8, &VL[buf][(j_ * 32 + w * 8) * 64]); \
    } \
  } while (0)

  STG_KV(0, 0);
  __syncthreads();

  for (int kt = 0; kt < nkt_blk; ++kt) {
    int cbuf = kt & 1;
    if (kt + 1 < nkt_blk) STG_KV(cbuf ^ 1, kt + 1);

    if (kt < nw) {
      bool diag = (kt == nw - 1);
      f32x4 s0[4] = {}, s1[4] = {};
      #pragma unroll
      for (int ks = 0; ks < 2; ++ks)
        #pragma unroll
        for (int nf = 0; nf < 4; ++nf) {
          int row = nf * 16 + lr;
          bf16x8 ak = __builtin_bit_cast(bf16x8,
              *(const s16x8*)&KL[cbuf][row * 64 + (((ks * 4 + g) ^ (lr & 7)) * 8)]);
          s0[nf] = __builtin_amdgcn_mfma_f32_16x16x32_bf16(ak, aq[0][ks], s0[nf], 0, 0, 0);
          s1[nf] = __builtin_amdgcn_mfma_f32_16x16x32_bf16(ak, aq[1][ks], s1[nf], 0, 0, 0);
        }

      bf16x8 ap0[2], ap1[2];
      sm_step(s0, m0, l0, accO[0], ap0, qbase + 0 * 16 + lr, kt * 64, diag, g);
      sm_step(s1, m1, l1, accO[1], ap1, qbase + 1 * 16 + lr, kt * 64, diag, g);

      #pragma unroll
      for (int ks = 0; ks < 2; ++ks)
        #pragma unroll
        for (int nfd = 0; nfd < 4; ++nfd) {
          int row = nfd * 16 + lr;
          int c1 = ks * 4 + (g >> 1), sub = (g & 1) * 4;
          uint2 lo = *(const uint2*)&VL[cbuf][row * 64 + ((c1 ^ (lr & 7)) * 8 + sub)];
          uint2 hi = *(const uint2*)&VL[cbuf][row * 64 + (((c1 + 2) ^ (lr & 7)) * 8 + sub)];
          union { uint4 u; bf16x8 v; } bb;
          bb.u = make_uint4(lo.x, lo.y, hi.x, hi.y);
          accO[0][nfd] = __builtin_amdgcn_mfma_f32_16x16x32_bf16(ap0[ks], bb.v, accO[0][nfd], 0, 0, 0);
          accO[1][nfd] = __builtin_amdgcn_mfma_f32_16x16x32_bf16(ap1[ks], bb.v, accO[1][nfd], 0, 0, 0);
        }
    }
    __syncthreads();
  }

  int b = bh >> 4, h = bh & 15;
  float li0 = 1.f / l0, li1 = 1.f / l1;
  #pragma unroll
  for (int st = 0; st < 2; ++st) {
    float lsrc = (st == 0) ? li0 : li1;
    #pragma unroll
    for (int reg = 0; reg < 4; ++reg) {
      float inv = __shfl(lsrc, g * 4 + reg);
      size_t row = (size_t)b * T_ + qbase + st * 16 + g * 4 + reg;
      #pragma unroll
      for (int nfd = 0; nfd < 4; ++nfd)
        y[row * E_ + h * 64 + nfd * 16 + lr] = f2bf(accO[st][nfd][reg] * inv);
    }
  }
  #undef STG_KV
}

// ---------------- orchestration ----------------
extern "C" void kernel_launch(void* const* d_in, const int* in_sizes, int n_in,
                              void* d_out, int out_size, void* d_ws, size_t ws_size,
                              hipStream_t stream) {
  const int*   idx   = (const int*)  d_in[0];
  const float* wte   = (const float*)d_in[1];
  const float* wpe   = (const float*)d_in[2];
  const float* ln1w  = (const float*)d_in[3];
  const float* ln1b  = (const float*)d_in[4];
  const float* attnw = (const float*)d_in[5];
  const float* attnb = (const float*)d_in[6];
  const float* projw = (const float*)d_in[7];
  const float* projb = (const float*)d_in[8];
  const float* ln2w  = (const float*)d_in[9];
  const float* ln2b  = (const float*)d_in[10];
  const float* fcw   = (const float*)d_in[11];
  const float* fcb   = (const float*)d_in[12];
  const float* fc2w  = (const float*)d_in[13];
  const float* fc2b  = (const float*)d_in[14];
  const float* lnfw  = (const float*)d_in[15];
  const float* lnfb  = (const float*)d_in[16];
  const float* lmw   = (const float*)d_in[17];
  float* out = (float*)d_out;

  char* p = (char*)d_ws;
  auto take = [&](size_t bytes) { char* r = p; p += (bytes + 255) & ~(size_t)255; return r; };
  ushort* wb_attn = (ushort*)take((size_t)L_ * 3 * E_ * E_ * 2);
  ushort* wb_proj = (ushort*)take((size_t)L_ * E_ * E_ * 2);
  ushort* wb_fc   = (ushort*)take((size_t)L_ * 4 * E_ * E_ * 2);
  ushort* wb_fc2  = (ushort*)take((size_t)L_ * E_ * 4 * E_ * 2);
  ushort* wb_lm   = (ushort*)take((size_t)V_ * E_ * 2);
  float*  x       = (float*) take((size_t)M_ * E_ * 4);
  ushort* hbuf    = (ushort*)take((size_t)M_ * E_ * 2);
  ushort* qb      = (ushort*)take((size_t)B_ * 16 * T_ * 64 * 2);
  ushort* kbuf    = (ushort*)take((size_t)B_ * 16 * T_ * 64 * 2);
  ushort* vtb     = (ushort*)take((size_t)B_ * 16 * T_ * 64 * 2);
  ushort* ybuf    = (ushort*)take((size_t)M_ * E_ * 2);
  ushort* mlp     = (ushort*)take((size_t)M_ * 4 * E_ * 2);
  ushort* pbh     = (ushort*)take((size_t)4 * M_ * E_ * 2);

  start_k<<<65152 + M_, 256, 0, stream>>>(attnw, projw, fcw, fc2w, lmw,
                                          wb_attn, wb_proj, wb_fc, wb_fc2, wb_lm,
                                          idx, wte, wpe, ln1w, ln1b, x, hbuf);

  for (int l = 0; l < L_; ++l) {
    gbt2_qkv<<<24 * 32, 256, 0, stream>>>(
        hbuf, wb_attn + (size_t)l * 3 * E_ * E_, attnb + l * 3 * E_, qb, kbuf, vtb);
    attn4_k<<<dim3(B_ * 16, T_ / 128), 256, 0, stream>>>(qb, kbuf, vtb, ybuf);
    gbt2_proj<<<8 * 32, 256, 0, stream>>>(
        ybuf, wb_proj + (size_t)l * E_ * E_, projb + l * E_, x, x);
    ln_k<<<M_, 256, 0, stream>>>(x, ln2w + l * E_, ln2b + l * E_, hbuf);
    gbt2_fc<<<32 * 32, 256, 0, stream>>>(
        hbuf, wb_fc + (size_t)l * 4 * E_ * E_, fcb + l * 4 * E_, mlp);
    gbt2_sk<<<4 * 8 * 32, 256, 0, stream>>>(mlp, wb_fc2 + (size_t)l * E_ * 4 * E_, pbh);
    if (l < L_ - 1)
      redln_k<<<M_, 256, 0, stream>>>(pbh, fc2b + l * E_, x,
                                      ln1w + (l + 1) * E_, ln1b + (l + 1) * E_, hbuf);
    else
      redln_k<<<M_, 256, 0, stream>>>(pbh, fc2b + l * E_, x, lnfw, lnfb, hbuf);
  }
  gemm8_lm<<<(V_ / 256) * (M_ / 256), 512, 0, stream>>>(hbuf, wb_lm, out);
}